// Round 3
// baseline (409.923 us; speedup 1.0000x reference)
//
#include <hip/hip_runtime.h>

typedef _Float16 half2_t __attribute__((ext_vector_type(2)));

// Problem constants
#define HDIM 256
#define WDIM 256
#define DDIM 64
#define HWSZ (HDIM*WDIM)          // 65536
#define NPIX 524288               // 8 * 65536

// Tiling: 32 wide x 16 tall, 512 threads, one pixel per thread.
#define TW 32
#define TH 16
#define BT 512
#define HW_T 38                   // TW+6
#define HH_T 22                   // TH+6
#define NPX 836                   // HW_T*HH_T halo pixels
#define DC 16                     // d-chunk size (16 halves = 32B/pixel/chunk)
#define NCH 4                     // 64/DC

// d_out layout (floats): dy, dx, conf_local, conf_global, local_weight, logits
#define OFF_DY   0
#define OFF_DX   524288
#define OFF_CONF 1048576
#define OFF_CG   1572864
#define OFF_LW   1572872
#define OFF_LG   2097160

// workspace layout (floats)
#define WS_GACC 0                 // 8*49 logit sums
#define WS_DYG  392
#define WS_DXG  400

struct alignas(16) H8 { half2_t v[4]; };   // 8 halves = one ds_read_b128

__global__ void zero_ws_k(float* __restrict__ ws) {
    const int i = threadIdx.x;
    if (i < 408) ws[i] = 0.f;
}

// __launch_bounds__(512,2): empirically (R2) 2nd arg acts as min-blocks/CU.
// 2 blocks x 8 waves = 16 waves/CU -> 128-VGPR cap; ~100 live regs fit, so
// accumulators stay in arch VGPRs (R2's (512,4) forced 64 VGPR -> AGPR shuffling).
__global__ void __launch_bounds__(BT, 2)
corr_main_k(const float* __restrict__ rub, const float* __restrict__ vis,
            const float* __restrict__ ltemp, float* __restrict__ out,
            float* __restrict__ ws)
{
    // Two fp16 "planes" per pixel: plane0 = d[0..7], plane1 = d[8..15] of the
    // current chunk. Within a plane, pixel stride = 16B -> consecutive lanes
    // read contiguous 16B blocks -> conflict-free ds_read_b128.
    __shared__ H8 vis_s[NPX * 2];           // 26752 B
    __shared__ float invv_s[NPX];           // 3344 B
    __shared__ float gacc_s[49];

    const int tid = threadIdx.x;
    const int tx  = tid & 31;
    const int ty  = tid >> 5;               // 0..15
    const int w0  = blockIdx.x * TW;
    const int h0  = blockIdx.y * TH;
    const int b   = blockIdx.z;
    const int ibase = b * (DDIM * HWSZ);

    if (tid < 49) gacc_s[tid] = 0.f;

    // Staging: thread covers halo px tid and tid+512 (clamped; duplicate
    // writes same value to same LDS slot -> benign).
    const bool val1 = (tid + BT) < NPX;
    const int px1c  = val1 ? (tid + BT) : (NPX - 1);
    auto halo_goff = [&](int px) -> int {
        const int hr = px / HW_T;
        const int wc = px - hr * HW_T;
        const int gh = min(HDIM - 1, max(0, h0 - 3 + hr));   // edge-replicate pad
        const int gw = min(WDIM - 1, max(0, w0 - 3 + wc));
        return gh * WDIM + gw;
    };
    const int goff0 = halo_goff(tid);
    const int goff1 = halo_goff(px1c);
    const int pown  = (h0 + ty) * WDIM + (w0 + tx);

    float acc[49];
#pragma unroll
    for (int k = 0; k < 49; ++k) acc[k] = 0.f;
    float sq0 = 0.f, sq1 = 0.f, sr = 0.f;

    // fp16-pair staging registers (1 VGPR each): vis halo x2, rubin cur/next.
    half2_t vv0[8], vv1[8], rcur[8], rnext[8];

    auto load_chunk = [&](int c, half2_t* v0, half2_t* v1, half2_t* rr) {
#pragma unroll
        for (int j = 0; j < 8; ++j) {
            const int gof0 = ibase + (c * DC + 2 * j) * HWSZ;
            const int gof1 = gof0 + HWSZ;
            half2_t a; a[0] = (_Float16)vis[gof0 + goff0]; a[1] = (_Float16)vis[gof1 + goff0];
            half2_t bb; bb[0] = (_Float16)vis[gof0 + goff1]; bb[1] = (_Float16)vis[gof1 + goff1];
            half2_t r; r[0] = (_Float16)rub[gof0 + pown];  r[1] = (_Float16)rub[gof1 + pown];
            v0[j] = a; v1[j] = bb; rr[j] = r;
        }
    };
    load_chunk(0, vv0, vv1, rcur);

    const int rowbase = ty * HW_T + tx;

#pragma unroll 1
    for (int c = 0; c < NCH; ++c) {
        __syncthreads();                    // WAR: prior compute done
        {
            H8 w;
            w.v[0] = vv0[0]; w.v[1] = vv0[1]; w.v[2] = vv0[2]; w.v[3] = vv0[3];
            vis_s[tid] = w;
            w.v[0] = vv0[4]; w.v[1] = vv0[5]; w.v[2] = vv0[6]; w.v[3] = vv0[7];
            vis_s[NPX + tid] = w;
            w.v[0] = vv1[0]; w.v[1] = vv1[1]; w.v[2] = vv1[2]; w.v[3] = vv1[3];
            vis_s[px1c] = w;
            w.v[0] = vv1[4]; w.v[1] = vv1[5]; w.v[2] = vv1[6]; w.v[3] = vv1[7];
            vis_s[NPX + px1c] = w;
        }
#pragma unroll
        for (int j = 0; j < 8; ++j) {
            sq0 = __builtin_amdgcn_fdot2(vv0[j], vv0[j], sq0, false);
            sq1 = __builtin_amdgcn_fdot2(vv1[j], vv1[j], sq1, false);
            sr  = __builtin_amdgcn_fdot2(rcur[j], rcur[j], sr, false);
        }
        __syncthreads();                    // LDS visible

        if (c < NCH - 1)                    // prefetch c+1 during compute
            load_chunk(c + 1, vv0, vv1, rnext);

        // 98 ds_read_b128 + 392 v_dot2_f32_f16 per chunk; offsets are
        // compile-time immediates off one base.
#pragma unroll
        for (int dyi = 0; dyi < 7; ++dyi) {
            const int rp = rowbase + dyi * HW_T;
#pragma unroll
            for (int dxi = 0; dxi < 7; ++dxi) {
                const H8 p = vis_s[rp + dxi];
                const H8 q = vis_s[NPX + rp + dxi];
                float a = acc[dyi * 7 + dxi];
                a = __builtin_amdgcn_fdot2(rcur[0], p.v[0], a, false);
                a = __builtin_amdgcn_fdot2(rcur[1], p.v[1], a, false);
                a = __builtin_amdgcn_fdot2(rcur[2], p.v[2], a, false);
                a = __builtin_amdgcn_fdot2(rcur[3], p.v[3], a, false);
                a = __builtin_amdgcn_fdot2(rcur[4], q.v[0], a, false);
                a = __builtin_amdgcn_fdot2(rcur[5], q.v[1], a, false);
                a = __builtin_amdgcn_fdot2(rcur[6], q.v[2], a, false);
                a = __builtin_amdgcn_fdot2(rcur[7], q.v[3], a, false);
                acc[dyi * 7 + dxi] = a;
            }
        }
#pragma unroll
        for (int j = 0; j < 8; ++j) rcur[j] = rnext[j];
    }

    // Publish vis inverse norms for the halo
    invv_s[tid] = 1.f / fmaxf(sqrtf(sq0), 1e-6f);
    if (val1) invv_s[tid + BT] = 1.f / fmaxf(sqrtf(sq1), 1e-6f);
    __syncthreads();

    const float tau  = fmaxf(__expf(ltemp[0]), 1e-3f);
    const float itau = 1.f / tau;
    const float invr = 1.f / fmaxf(sqrtf(sr), 1e-6f);
    const float cR   = invr * 0.125f;        // scale = 1/sqrt(64)
    const float uu   = 1.f / 49.f;
    const float i1mu = 49.f / 48.f;

    const int h = h0 + ty, w = w0 + tx;
    const int lgbase = OFF_LG + b * 49 * HWSZ + h * WDIM + w;
    float mlg = -1e30f;
#pragma unroll
    for (int dyi = 0; dyi < 7; ++dyi) {
        const int rowb = (ty + dyi) * HW_T + tx;
#pragma unroll
        for (int dxi = 0; dxi < 7; ++dxi) {
            const int k = dyi * 7 + dxi;
            const float lg = acc[k] * cR * invv_s[rowb + dxi];
            out[lgbase + k * HWSZ] = lg;
            acc[k] = lg;                     // keep logit for global reduction
            mlg = fmaxf(mlg, lg);
        }
    }
    const float m = mlg * itau;
    float S = 0.f, sdy = 0.f, sdx = 0.f;
#pragma unroll
    for (int dyi = 0; dyi < 7; ++dyi) {
#pragma unroll
        for (int dxi = 0; dxi < 7; ++dxi) {
            const float e = __expf(fmaf(acc[dyi * 7 + dxi], itau, -m));
            S += e;
            sdy += e * (float)(dyi - 3);
            sdx += e * (float)(dxi - 3);
        }
    }
    const float invS = 1.f / S;
    const float conf = invS;                 // max prob = exp(0)/S
    const float lw   = fminf(fmaxf((conf - uu) * i1mu, 0.f), 1.f);
    const int po = b * HWSZ + h * WDIM + w;
    out[OFF_CONF + po] = conf;
    out[OFF_LW   + po] = lw;
    out[OFF_DY   + po] = sdy * invS;         // local; combine_k blends with global
    out[OFF_DX   + po] = sdx * invS;

    // Global branch: wave butterfly -> LDS atomic -> one global atomic per block
#pragma unroll
    for (int k = 0; k < 49; ++k) {
        float v = acc[k];
#pragma unroll
        for (int off = 32; off > 0; off >>= 1)
            v += __shfl_xor(v, off, 64);
        if ((tid & 63) == 0) atomicAdd(&gacc_s[k], v);
    }
    __syncthreads();
    if (tid < 49) atomicAdd(&ws[WS_GACC + b * 49 + tid], gacc_s[tid]);
}

__global__ void glob_branch_k(const float* __restrict__ ltemp,
                              float* __restrict__ out, float* __restrict__ ws)
{
    const int t = threadIdx.x;
    if (t >= 8) return;
    const float tau  = fmaxf(__expf(ltemp[0]), 1e-3f);
    const float itau = 1.f / tau;
    float tk[49];
    float m = -1e30f;
#pragma unroll
    for (int k = 0; k < 49; ++k) {
        const float mean = ws[WS_GACC + t * 49 + k] * (1.f / 65536.f);
        tk[k] = mean * itau;
        m = fmaxf(m, tk[k]);
    }
    float S = 0.f, sdy = 0.f, sdx = 0.f;
#pragma unroll
    for (int k = 0; k < 49; ++k) {
        const float e = __expf(tk[k] - m);
        S += e;
        sdy += e * (float)(k / 7 - 3);
        sdx += e * (float)(k % 7 - 3);
    }
    const float invS = 1.f / S;
    out[OFF_CG + t] = invS;                  // conf_global
    ws[WS_DYG + t] = sdy * invS;
    ws[WS_DXG + t] = sdx * invS;
}

__global__ void combine_k(float* __restrict__ out, const float* __restrict__ ws)
{
    const int gid = blockIdx.x * 256 + threadIdx.x;
    if (gid >= NPIX) return;
    const int b = gid >> 16;
    const float lw  = out[OFF_LW + gid];
    const float dyl = out[OFF_DY + gid];
    const float dxl = out[OFF_DX + gid];
    out[OFF_DY + gid] = lw * dyl + (1.f - lw) * ws[WS_DYG + b];
    out[OFF_DX + gid] = lw * dxl + (1.f - lw) * ws[WS_DXG + b];
}

extern "C" void kernel_launch(void* const* d_in, const int* in_sizes, int n_in,
                              void* d_out, int out_size, void* d_ws, size_t ws_size,
                              hipStream_t stream)
{
    const float* rub = (const float*)d_in[0];
    const float* vis = (const float*)d_in[1];
    const float* lt  = (const float*)d_in[2];
    float* out = (float*)d_out;
    float* ws  = (float*)d_ws;

    hipLaunchKernelGGL(zero_ws_k, dim3(1), dim3(512), 0, stream, ws);
    hipLaunchKernelGGL(corr_main_k, dim3(WDIM / TW, HDIM / TH, 8), dim3(BT), 0, stream,
                       rub, vis, lt, out, ws);
    hipLaunchKernelGGL(glob_branch_k, dim3(1), dim3(64), 0, stream, lt, out, ws);
    hipLaunchKernelGGL(combine_k, dim3(NPIX / 256), dim3(256), 0, stream, out, ws);
}